// Round 6
// baseline (937.407 us; speedup 1.0000x reference)
//
#include <hip/hip_runtime.h>
#include <hip/hip_bf16.h>
#include <stdint.h>

typedef __attribute__((ext_vector_type(8))) short bf16x8;
typedef __attribute__((ext_vector_type(4))) float f32x4;
typedef __attribute__((ext_vector_type(4))) int i32x4;

constexpr int Mdim = 8192;
constexpr int Ndim = 11008;
constexpr int Kdim = 4096;
constexpr int NT = Kdim / 64;            // 64 K-tiles of BK=64

__device__ __forceinline__ unsigned short f2bf(float f) {
    __bf16 h = (__bf16)f;
    return __builtin_bit_cast(unsigned short, h);
}

__device__ __forceinline__ void gload16(const unsigned short* g, unsigned short* lds) {
    __builtin_amdgcn_global_load_lds(
        (const __attribute__((address_space(1))) unsigned int*)g,
        (__attribute__((address_space(3))) unsigned int*)lds,
        16, 0, 0);
}

// ---------------- prepass 1: A fp32 -> bf16 ----------------
__global__ __launch_bounds__(256) void cvtA_kernel(const float* __restrict__ A,
                                                   unsigned short* __restrict__ Ab)
{
    const size_t total8 = (size_t)Mdim * Kdim / 8;
    for (size_t i = (size_t)blockIdx.x * blockDim.x + threadIdx.x; i < total8;
         i += (size_t)gridDim.x * blockDim.x) {
        const float* src = A + i * 8;
        const f32x4 x0 = *(const f32x4*)src;
        const f32x4 x1 = *(const f32x4*)(src + 4);
        union { bf16x8 v; unsigned short u[8]; } h;
        h.u[0] = f2bf(x0[0]); h.u[1] = f2bf(x0[1]);
        h.u[2] = f2bf(x0[2]); h.u[3] = f2bf(x0[3]);
        h.u[4] = f2bf(x1[0]); h.u[5] = f2bf(x1[1]);
        h.u[6] = f2bf(x1[2]); h.u[7] = f2bf(x1[3]);
        *(bf16x8*)(Ab + i * 8) = h.v;
    }
}

// ---------------- prepass 2: W int4 -> dequant bf16, transposed to [N][K] ----------------
__global__ __launch_bounds__(256) void deqW_kernel(const int* __restrict__ Wq,
                                                   const float* __restrict__ Ws,
                                                   unsigned short* __restrict__ Wt)
{
    __shared__ unsigned short T[64][72];
    const int kt = blockIdx.x % (Kdim / 64);
    const int nt = blockIdx.x / (Kdim / 64);
    const int k0 = kt * 64, n0 = nt * 64;
    const int t = threadIdx.x;

    const int pr   = t >> 3;
    const int nloc = (t & 7) * 8;
    const int* wp = Wq + (size_t)(k0 / 2 + pr) * Ndim + n0 + nloc;
    const i32x4 ra = *(const i32x4*)wp;
    const i32x4 rb = *(const i32x4*)(wp + 4);
    const int g = (k0 + 2 * pr) >> 5;
    const float* sp = Ws + (size_t)g * Ndim + n0 + nloc;
    const f32x4 s0 = *(const f32x4*)sp;
    const f32x4 s1 = *(const f32x4*)(sp + 4);
#pragma unroll
    for (int i = 0; i < 8; ++i) {
        const int v = (i < 4) ? ra[i] : rb[i - 4];
        const float s = (i < 4) ? s0[i] : s1[i - 4];
        union { unsigned int w; unsigned short u[2]; } o;
        o.u[0] = f2bf((float)((v & 15) - 8) * s);
        o.u[1] = f2bf((float)(((v >> 4) & 15) - 8) * s);
        *(unsigned int*)&T[nloc + i][2 * pr] = o.w;
    }
    __syncthreads();
    const int nl = t >> 2;
    const int ko = (t & 3) * 16;
    bf16x8 o0 = *(const bf16x8*)&T[nl][ko];
    bf16x8 o1 = *(const bf16x8*)&T[nl][ko + 8];
    unsigned short* dst = Wt + (size_t)(n0 + nl) * Kdim + k0 + ko;
    *(bf16x8*)dst = o0;
    *(bf16x8*)(dst + 8) = o1;
}

// ---------------- main GEMM: 256x128x64, 8 waves (4x2), 2 barriers/K-tile ----------------
__global__ __launch_bounds__(512, 2) void gemm256_kernel(
    const unsigned short* __restrict__ Ab,
    const unsigned short* __restrict__ Bt,
    const float* __restrict__ Bias,
    float* __restrict__ Out)
{
    // A: 4 slots (dbuf x half) of 128x64 bf16 = 64 KB; B: 4 slots of 64x64 = 32 KB. 96 KiB.
    __shared__ unsigned short sh[49152];

    const int tid  = threadIdx.x;
    const int lane = tid & 63;
    const int wid  = tid >> 6;
    const int wr   = wid >> 1;               // 0..3 : M 64-row strip
    const int wc   = wid & 1;                // 0..1 : N 64-col half
    const int l15  = lane & 15;
    const int l4   = lane >> 4;
    const int swz  = (l15 & 7) << 3;

    // XCD-aware bijective swizzle (2752 % 8 == 0), bm-major chunks per XCD
    const int nwg = (Mdim / 256) * (Ndim / 128);   // 2752
    const int cpx = nwg / 8;                        // 344
    const int wg  = ((int)blockIdx.x % 8) * cpx + (int)blockIdx.x / 8;
    const int nbn = Ndim / 128;                     // 86
    const int bm = wg / nbn, bn = wg % nbn;
    const int m0 = bm * 256, n0 = bn * 128;

    // staging per-thread addresses (pre-swizzled source, linear LDS dest)
    const int sr  = tid >> 3;                       // 0..63
    const int scl = ((tid & 7) * 8) ^ ((sr & 7) << 3);
    const int ldo = sr * 64 + (tid & 7) * 8;        // shorts
    const unsigned short* aSrc = Ab + (size_t)(m0 + sr) * Kdim + scl;
    const unsigned short* bSrc = Bt + (size_t)(n0 + sr) * Kdim + scl;

    // A slot s at s*8192; covers 128 rows (j=0: rows 0..63, j=1: 64..127)
    auto stageA = [&](int tt, int h) {
        unsigned short* base = &sh[((tt & 1) * 2 + h) * 8192];
#pragma unroll
        for (int j = 0; j < 2; ++j)
            gload16(aSrc + (size_t)(h * 128 + 64 * j) * Kdim + tt * 64, base + ldo + j * 4096);
    };
    // B slot s at 32768 + s*4096; covers 64 rows
    auto stageB = [&](int tt, int h) {
        unsigned short* base = &sh[32768 + ((tt & 1) * 2 + h) * 4096];
        gload16(bSrc + (size_t)(h * 64) * Kdim + tt * 64, base + ldo);
    };

    f32x4 acc[4][4];
#pragma unroll
    for (int i = 0; i < 4; ++i)
#pragma unroll
        for (int j = 0; j < 4; ++j) acc[i][j] = (f32x4){0.f, 0.f, 0.f, 0.f};

    // prologue: tile0 A+B, tile1 B; wait tile0 (leave B(1) in flight); barrier
    stageA(0, 0); stageA(0, 1);
    stageB(0, 0); stageB(0, 1);
    stageB(1, 0); stageB(1, 1);
    asm volatile("s_waitcnt vmcnt(2)" ::: "memory");
    __builtin_amdgcn_s_barrier();

    for (int t = 0; t < NT; ++t) {
        const int par = t & 1, parn = par ^ 1;
        const unsigned short* aslot = &sh[(par * 2 + (wr >> 1)) * 8192];
        const unsigned short* bslot = &sh[32768 + (par * 2 + wc) * 4096];

        // ---- issue all reads: B first (8), then A fm0,1 (4), A fm2,3 (4) ----
        bf16x8 bfr[4][2], af[4][2];
#pragma unroll
        for (int fn = 0; fn < 4; ++fn)
#pragma unroll
            for (int ks = 0; ks < 2; ++ks) {
                const int r = fn * 16 + l15;
                bfr[fn][ks] = *(const bf16x8*)&bslot[r * 64 + ((ks * 32 + l4 * 8) ^ swz)];
            }
#pragma unroll
        for (int fm = 0; fm < 4; ++fm)
#pragma unroll
            for (int ks = 0; ks < 2; ++ks) {
                const int r = (wr & 1) * 64 + fm * 16 + l15;
                af[fm][ks] = *(const bf16x8*)&aslot[r * 64 + ((ks * 32 + l4 * 8) ^ swz)];
            }

        // all waves' B reads complete -> safe to DMA-overwrite B par-slot after barrier
        asm volatile("s_waitcnt lgkmcnt(8)" ::: "memory");
        __builtin_amdgcn_s_barrier();

        // ---- issue stage loads: A(t+1) -> parn slots, B(t+2) -> par slots ----
        if (t + 1 < NT) { stageA(t + 1, 0); stageA(t + 1, 1); }
        if (t + 2 < NT) { stageB(t + 2, 0); stageB(t + 2, 1); }

        asm volatile("s_waitcnt lgkmcnt(4)" ::: "memory");
        __builtin_amdgcn_sched_barrier(0);
        __builtin_amdgcn_s_setprio(1);
#pragma unroll
        for (int fm = 0; fm < 2; ++fm)
#pragma unroll
            for (int fn = 0; fn < 4; ++fn)
#pragma unroll
                for (int ks = 0; ks < 2; ++ks)
                    acc[fm][fn] = __builtin_amdgcn_mfma_f32_16x16x32_bf16(
                        af[fm][ks], bfr[fn][ks], acc[fm][fn], 0, 0, 0);

        asm volatile("s_waitcnt lgkmcnt(0)" ::: "memory");
        __builtin_amdgcn_sched_barrier(0);
#pragma unroll
        for (int fm = 2; fm < 4; ++fm)
#pragma unroll
            for (int fn = 0; fn < 4; ++fn)
#pragma unroll
                for (int ks = 0; ks < 2; ++ks)
                    acc[fm][fn] = __builtin_amdgcn_mfma_f32_16x16x32_bf16(
                        af[fm][ks], bfr[fn][ks], acc[fm][fn], 0, 0, 0);
        __builtin_amdgcn_s_setprio(0);

        // counted vmcnt: oldest 6 of 8 outstanding = A(t+1)+B(t+1); leave B(t+2)
        if (t < NT - 2)       asm volatile("s_waitcnt vmcnt(2)" ::: "memory");
        else if (t == NT - 2) asm volatile("s_waitcnt vmcnt(0)" ::: "memory");
        asm volatile("" ::: "memory");
        __builtin_amdgcn_s_barrier();
    }

    // ---- epilogue: C/D col = lane&15, row = (lane>>4)*4 + r ----
    const int rb = l4 * 4;
    float bv[4];
#pragma unroll
    for (int fn = 0; fn < 4; ++fn)
        bv[fn] = Bias[n0 + wc * 64 + fn * 16 + l15];
#pragma unroll
    for (int fm = 0; fm < 4; ++fm) {
        const size_t mg = (size_t)(m0 + wr * 64 + fm * 16 + rb);
#pragma unroll
        for (int fn = 0; fn < 4; ++fn) {
            const int ng = n0 + wc * 64 + fn * 16 + l15;
            const float b = bv[fn];
#pragma unroll
            for (int r = 0; r < 4; ++r)
                __builtin_nontemporal_store(acc[fm][fn][r] + b,
                                            &Out[(mg + r) * Ndim + ng]);
        }
    }
}

// ---------------- fallback: fused kernel (if ws too small) ----------------
constexpr int SA = 72;
__global__ __launch_bounds__(256) void w4a32_fused_kernel(
    const float* __restrict__ A,
    const int* __restrict__ Wq,
    const float* __restrict__ Ws,
    const float* __restrict__ Bias,
    float* __restrict__ Out)
{
    __shared__ unsigned short As[128 * SA];
    __shared__ unsigned short Bs[128 * SA];
    const int tid = threadIdx.x;
    const int nbn = Ndim / 128;
    const int bn = blockIdx.x % nbn;
    const int bm = blockIdx.x / nbn;
    const int m0 = bm * 128, n0 = bn * 128;
    const int lane = tid & 63;
    const int wid  = tid >> 6;
    const int wr   = wid >> 1;
    const int wc   = wid & 1;
    const int l15  = lane & 15;
    const int l4   = lane >> 4;
    f32x4 acc[4][4];
#pragma unroll
    for (int i = 0; i < 4; ++i)
#pragma unroll
        for (int j = 0; j < 4; ++j) acc[i][j] = (f32x4){0.f, 0.f, 0.f, 0.f};
    const int a_tr = tid >> 3;
    const int a_tc = (tid & 7) * 8;
    const int kp2  = tid >> 4;
    const int n8   = (tid & 15) * 8;
    for (int kt = 0; kt < Kdim / 64; ++kt) {
        const int k0 = kt * 64;
        __syncthreads();
#pragma unroll
        for (int j = 0; j < 4; ++j) {
            const int ml = a_tr + 32 * j;
            const float* src = A + (size_t)(m0 + ml) * Kdim + (k0 + a_tc);
            const f32x4 x0 = *(const f32x4*)src;
            const f32x4 x1 = *(const f32x4*)(src + 4);
            union { bf16x8 v; unsigned short u[8]; } h;
            h.u[0] = f2bf(x0[0]); h.u[1] = f2bf(x0[1]);
            h.u[2] = f2bf(x0[2]); h.u[3] = f2bf(x0[3]);
            h.u[4] = f2bf(x1[0]); h.u[5] = f2bf(x1[1]);
            h.u[6] = f2bf(x1[2]); h.u[7] = f2bf(x1[3]);
            *(bf16x8*)(&As[ml * SA + (a_tc ^ ((ml & 7) << 3))]) = h.v;
        }
        {
            const int pr = kt * 32 + 2 * kp2;
            const int* wp = Wq + (size_t)pr * Ndim + (n0 + n8);
            const i32x4 r0a = *(const i32x4*)wp;
            const i32x4 r0b = *(const i32x4*)(wp + 4);
            const i32x4 r1a = *(const i32x4*)(wp + Ndim);
            const i32x4 r1b = *(const i32x4*)(wp + Ndim + 4);
            const int g = 2 * kt + (kp2 >> 3);
            const float* sp = Ws + (size_t)g * Ndim + (n0 + n8);
            const f32x4 s0 = *(const f32x4*)sp;
            const f32x4 s1 = *(const f32x4*)(sp + 4);
#pragma unroll
            for (int i = 0; i < 8; ++i) {
                const float s = (i < 4) ? s0[i] : s1[i - 4];
                const int b0 = (i < 4) ? r0a[i] : r0b[i - 4];
                const int b1 = (i < 4) ? r1a[i] : r1b[i - 4];
                union { unsigned long long v; unsigned short u[4]; } o;
                o.u[0] = f2bf((float)((b0 & 15) - 8) * s);
                o.u[1] = f2bf((float)(((b0 >> 4) & 15) - 8) * s);
                o.u[2] = f2bf((float)((b1 & 15) - 8) * s);
                o.u[3] = f2bf((float)(((b1 >> 4) & 15) - 8) * s);
                const int nl = n8 + i;
                const int swzz = ((nl ^ (nl >> 3)) & 7) << 3;
                *(unsigned long long*)(&Bs[nl * SA + ((4 * kp2) ^ swzz)]) = o.v;
            }
        }
        __syncthreads();
#pragma unroll
        for (int ks = 0; ks < 2; ++ks) {
            const int kb  = ks * 32 + l4 * 8;
            const int swa = (l15 & 7) << 3;
            bf16x8 af[4], bfr[4];
#pragma unroll
            for (int fm = 0; fm < 4; ++fm) {
                const int row = wr * 64 + fm * 16 + l15;
                af[fm] = *(const bf16x8*)(&As[row * SA + (kb ^ swa)]);
            }
#pragma unroll
            for (int fn = 0; fn < 4; ++fn) {
                const int nrow = wc * 64 + fn * 16 + l15;
                const int swb = ((nrow ^ (nrow >> 3)) & 7) << 3;
                bfr[fn] = *(const bf16x8*)(&Bs[nrow * SA + (kb ^ swb)]);
            }
#pragma unroll
            for (int fm = 0; fm < 4; ++fm)
#pragma unroll
                for (int fn = 0; fn < 4; ++fn)
                    acc[fm][fn] = __builtin_amdgcn_mfma_f32_16x16x32_bf16(
                        af[fm], bfr[fn], acc[fm][fn], 0, 0, 0);
        }
    }
    const int rb = l4 * 4;
    float bv[4];
#pragma unroll
    for (int fn = 0; fn < 4; ++fn)
        bv[fn] = Bias[n0 + wc * 64 + fn * 16 + l15];
#pragma unroll
    for (int fm = 0; fm < 4; ++fm) {
        const size_t mg = (size_t)(m0 + wr * 64 + fm * 16 + rb);
#pragma unroll
        for (int fn = 0; fn < 4; ++fn) {
            const int ng = n0 + wc * 64 + fn * 16 + l15;
            const float b = bv[fn];
#pragma unroll
            for (int r = 0; r < 4; ++r)
                Out[(mg + r) * Ndim + ng] = acc[fm][fn][r] + b;
        }
    }
}

extern "C" void kernel_launch(void* const* d_in, const int* in_sizes, int n_in,
                              void* d_out, int out_size, void* d_ws, size_t ws_size,
                              hipStream_t stream) {
    const float* A    = (const float*)d_in[0];
    const int* Wq     = (const int*)d_in[1];
    const float* Ws   = (const float*)d_in[2];
    const float* Bias = (const float*)d_in[3];
    float* Out        = (float*)d_out;

    const size_t needA = (size_t)Mdim * Kdim * 2;
    const size_t needW = (size_t)Ndim * Kdim * 2;
    if (ws_size >= needA + needW) {
        unsigned short* Ab = (unsigned short*)d_ws;
        unsigned short* Wt = (unsigned short*)((char*)d_ws + needA);
        cvtA_kernel<<<4096, 256, 0, stream>>>(A, Ab);
        deqW_kernel<<<(Kdim / 64) * (Ndim / 64), 256, 0, stream>>>(Wq, Ws, Wt);
        gemm256_kernel<<<(Mdim / 256) * (Ndim / 128), 512, 0, stream>>>(Ab, Wt, Bias, Out);
    } else {
        w4a32_fused_kernel<<<(Mdim / 128) * (Ndim / 128), 256, 0, stream>>>(A, Wq, Ws, Bias, Out);
    }
}

// Round 7
// 773.735 us; speedup vs baseline: 1.2115x; 1.2115x over previous
//
#include <hip/hip_runtime.h>
#include <hip/hip_bf16.h>
#include <stdint.h>

typedef __attribute__((ext_vector_type(8))) short bf16x8;
typedef __attribute__((ext_vector_type(4))) float f32x4;
typedef __attribute__((ext_vector_type(4))) int i32x4;

constexpr int Mdim = 8192;
constexpr int Ndim = 11008;
constexpr int Kdim = 4096;
constexpr int NT = Kdim / 64;            // 64 K-tiles of BK=64

__device__ __forceinline__ unsigned short f2bf(float f) {
    __bf16 h = (__bf16)f;
    return __builtin_bit_cast(unsigned short, h);
}

__device__ __forceinline__ void gload16(const unsigned short* g, unsigned short* lds) {
    __builtin_amdgcn_global_load_lds(
        (const __attribute__((address_space(1))) unsigned int*)g,
        (__attribute__((address_space(3))) unsigned int*)lds,
        16, 0, 0);
}

// ---------------- prepass 1: A fp32 -> bf16 ----------------
__global__ __launch_bounds__(256) void cvtA_kernel(const float* __restrict__ A,
                                                   unsigned short* __restrict__ Ab)
{
    const size_t total8 = (size_t)Mdim * Kdim / 8;
    for (size_t i = (size_t)blockIdx.x * blockDim.x + threadIdx.x; i < total8;
         i += (size_t)gridDim.x * blockDim.x) {
        const float* src = A + i * 8;
        const f32x4 x0 = *(const f32x4*)src;
        const f32x4 x1 = *(const f32x4*)(src + 4);
        union { bf16x8 v; unsigned short u[8]; } h;
        h.u[0] = f2bf(x0[0]); h.u[1] = f2bf(x0[1]);
        h.u[2] = f2bf(x0[2]); h.u[3] = f2bf(x0[3]);
        h.u[4] = f2bf(x1[0]); h.u[5] = f2bf(x1[1]);
        h.u[6] = f2bf(x1[2]); h.u[7] = f2bf(x1[3]);
        *(bf16x8*)(Ab + i * 8) = h.v;
    }
}

// ---------------- prepass 2: W int4 -> dequant bf16, transposed to [N][K] ----------------
__global__ __launch_bounds__(256) void deqW_kernel(const int* __restrict__ Wq,
                                                   const float* __restrict__ Ws,
                                                   unsigned short* __restrict__ Wt)
{
    __shared__ unsigned short T[64][72];
    const int kt = blockIdx.x % (Kdim / 64);
    const int nt = blockIdx.x / (Kdim / 64);
    const int k0 = kt * 64, n0 = nt * 64;
    const int t = threadIdx.x;

    const int pr   = t >> 3;
    const int nloc = (t & 7) * 8;
    const int* wp = Wq + (size_t)(k0 / 2 + pr) * Ndim + n0 + nloc;
    const i32x4 ra = *(const i32x4*)wp;
    const i32x4 rb = *(const i32x4*)(wp + 4);
    const int g = (k0 + 2 * pr) >> 5;
    const float* sp = Ws + (size_t)g * Ndim + n0 + nloc;
    const f32x4 s0 = *(const f32x4*)sp;
    const f32x4 s1 = *(const f32x4*)(sp + 4);
#pragma unroll
    for (int i = 0; i < 8; ++i) {
        const int v = (i < 4) ? ra[i] : rb[i - 4];
        const float s = (i < 4) ? s0[i] : s1[i - 4];
        union { unsigned int w; unsigned short u[2]; } o;
        o.u[0] = f2bf((float)((v & 15) - 8) * s);
        o.u[1] = f2bf((float)(((v >> 4) & 15) - 8) * s);
        *(unsigned int*)&T[nloc + i][2 * pr] = o.w;
    }
    __syncthreads();
    const int nl = t >> 2;
    const int ko = (t & 3) * 16;
    bf16x8 o0 = *(const bf16x8*)&T[nl][ko];
    bf16x8 o1 = *(const bf16x8*)&T[nl][ko + 8];
    unsigned short* dst = Wt + (size_t)(n0 + nl) * Kdim + k0 + ko;
    *(bf16x8*)dst = o0;
    *(bf16x8*)(dst + 8) = o1;
}

// ---------------- main GEMM: 256x256x64, 8 waves, 4 phases/K-tile, 2 barriers/K-tile ----------------
__global__ __launch_bounds__(512, 2) void gemm256_kernel(
    const unsigned short* __restrict__ Ab,
    const unsigned short* __restrict__ Bt,
    const float* __restrict__ Bias,
    float* __restrict__ Out)
{
    // LDS: A region 4 slots (par,half) of 128x64 bf16, then B region 4 slots. 128 KiB.
    __shared__ unsigned short sh[65536];

    const int tid  = threadIdx.x;
    const int lane = tid & 63;
    const int wid  = tid >> 6;
    const int wr   = wid >> 2;               // 0..1 : M 128-row half
    const int wc   = wid & 3;                // 0..3 : N 64-col quarter
    const int l15  = lane & 15;
    const int l4   = lane >> 4;
    const int swz  = (l15 & 7) << 3;
    const int kb0  = l4 * 8;
    const int kb1  = 32 + l4 * 8;

    // XCD-aware bijective swizzle (1376 % 8 == 0), bm-major chunks per XCD
    const int nwg = (Mdim / 256) * (Ndim / 256);   // 1376
    const int cpx = nwg / 8;                        // 172
    const int wg  = ((int)blockIdx.x % 8) * cpx + (int)blockIdx.x / 8;
    const int nbn = Ndim / 256;                     // 43
    const int bm = wg / nbn, bn = wg % nbn;
    const int m0 = bm * 256, n0 = bn * 256;

    // staging per-thread addresses (pre-swizzled source, linear LDS dest)
    const int sr  = tid >> 3;                       // 0..63
    const int scl = ((tid & 7) * 8) ^ ((sr & 7) << 3);
    const int ldo = sr * 64 + (tid & 7) * 8;        // shorts; + j*4096
    const unsigned short* aSrc = Ab + (size_t)(m0 + sr) * Kdim + scl;
    const unsigned short* bSrc = Bt + (size_t)(n0 + sr) * Kdim + scl;

    auto stageA = [&](int tt, int h, int slot) {
        unsigned short* base = &sh[slot * 8192];
#pragma unroll
        for (int j = 0; j < 2; ++j)
            gload16(aSrc + (size_t)(h * 128 + 64 * j) * Kdim + tt * 64, base + ldo + j * 4096);
    };
    auto stageB = [&](int tt, int h, int slot) {
        unsigned short* base = &sh[32768 + slot * 8192];
#pragma unroll
        for (int j = 0; j < 2; ++j)
            gload16(bSrc + (size_t)(h * 128 + 64 * j) * Kdim + tt * 64, base + ldo + j * 4096);
    };

    f32x4 acc[8][4];
#pragma unroll
    for (int i = 0; i < 8; ++i)
#pragma unroll
        for (int j = 0; j < 4; ++j) acc[i][j] = (f32x4){0.f, 0.f, 0.f, 0.f};

    // prologue: tile0 (A0,A1,B0,B1) + tile1 B halves; wait tile0; barrier
    stageA(0, 0, 0); stageA(0, 1, 1);
    stageB(0, 0, 0); stageB(0, 1, 1);
    stageB(1, 0, 2); stageB(1, 1, 3);
    asm volatile("s_waitcnt vmcnt(4)" ::: "memory");
    __builtin_amdgcn_s_barrier();

    const int browb = (wc & 1) * 64;

    for (int t = 0; t < NT; ++t) {
        const int par = t & 1, parn = par ^ 1;
        const unsigned short* aslot = &sh[(par * 2 + wr) * 8192];
        const unsigned short* bslot = &sh[32768 + (par * 2 + (wc >> 1)) * 8192];
        bf16x8 bf[4][2];

#pragma unroll
        for (int p = 0; p < 4; ++p) {
            // ---- ds_read this phase's A quadrant (B once, at p0) ----
            bf16x8 af[2][2];
#pragma unroll
            for (int q = 0; q < 2; ++q) {
                const int row = (2 * p + q) * 16 + l15;
                af[q][0] = *(const bf16x8*)&aslot[row * 64 + (kb0 ^ swz)];
                af[q][1] = *(const bf16x8*)&aslot[row * 64 + (kb1 ^ swz)];
            }
            if (p == 0) {
#pragma unroll
                for (int fn = 0; fn < 4; ++fn) {
                    const int row = browb + fn * 16 + l15;
                    bf[fn][0] = *(const bf16x8*)&bslot[row * 64 + (kb0 ^ swz)];
                    bf[fn][1] = *(const bf16x8*)&bslot[row * 64 + (kb1 ^ swz)];
                }
            }
            // ---- issue one half-tile stage per phase ----
            // A(t+1) -> parn slots (readers finished before last end-barrier);
            // B(t+2) -> par slots (readers this tile@p0, ordered by mid-barrier).
            if (p == 0 && t + 1 < NT) stageA(t + 1, 0, parn * 2 + 0);
            if (p == 1 && t + 1 < NT) stageA(t + 1, 1, parn * 2 + 1);
            if (p == 2 && t + 2 < NT) stageB(t + 2, 0, par * 2 + 0);
            if (p == 3 && t + 2 < NT) stageB(t + 2, 1, par * 2 + 1);

            asm volatile("s_waitcnt lgkmcnt(0)" ::: "memory");
            __builtin_amdgcn_sched_barrier(0);

            __builtin_amdgcn_s_setprio(1);
#pragma unroll
            for (int q = 0; q < 2; ++q)
#pragma unroll
                for (int fn = 0; fn < 4; ++fn) {
                    acc[2 * p + q][fn] = __builtin_amdgcn_mfma_f32_16x16x32_bf16(
                        af[q][0], bf[fn][0], acc[2 * p + q][fn], 0, 0, 0);
                    acc[2 * p + q][fn] = __builtin_amdgcn_mfma_f32_16x16x32_bf16(
                        af[q][1], bf[fn][1], acc[2 * p + q][fn], 0, 0, 0);
                }
            __builtin_amdgcn_s_setprio(0);

            if (p == 1) {
                // mid-barrier: all waves' B(t) (and p0/p1 A) reads are complete
                // (each wave's lgkmcnt(0) precedes its MFMA precedes this barrier)
                asm volatile("" ::: "memory");
                __builtin_amdgcn_s_barrier();
            }
            if (p == 3) {
                // counted wait: oldest 8 of 12 outstanding = A(t+1)+B(t+1); leave B(t+2)
                if (t < NT - 2)       asm volatile("s_waitcnt vmcnt(4)" ::: "memory");
                else if (t == NT - 2) asm volatile("s_waitcnt vmcnt(0)" ::: "memory");
                asm volatile("" ::: "memory");
                __builtin_amdgcn_s_barrier();   // end-barrier: staged data visible to all
            }
        }
    }

    // ---- epilogue: C/D col = lane&15, row = (lane>>4)*4 + r ----
    const int rb = l4 * 4;
    float bv[4];
#pragma unroll
    for (int fn = 0; fn < 4; ++fn)
        bv[fn] = Bias[n0 + wc * 64 + fn * 16 + l15];
#pragma unroll
    for (int fm = 0; fm < 8; ++fm) {
        const size_t mg = (size_t)(m0 + wr * 128 + fm * 16 + rb);
#pragma unroll
        for (int fn = 0; fn < 4; ++fn) {
            const int ng = n0 + wc * 64 + fn * 16 + l15;
            const float b = bv[fn];
#pragma unroll
            for (int r = 0; r < 4; ++r)
                Out[(mg + r) * Ndim + ng] = acc[fm][fn][r] + b;
        }
    }
}

// ---------------- fallback: fused kernel (if ws too small) ----------------
constexpr int SA = 72;
__global__ __launch_bounds__(256) void w4a32_fused_kernel(
    const float* __restrict__ A,
    const int* __restrict__ Wq,
    const float* __restrict__ Ws,
    const float* __restrict__ Bias,
    float* __restrict__ Out)
{
    __shared__ unsigned short As[128 * SA];
    __shared__ unsigned short Bs[128 * SA];
    const int tid = threadIdx.x;
    const int nbn = Ndim / 128;
    const int bn = blockIdx.x % nbn;
    const int bm = blockIdx.x / nbn;
    const int m0 = bm * 128, n0 = bn * 128;
    const int lane = tid & 63;
    const int wid  = tid >> 6;
    const int wr   = wid >> 1;
    const int wc   = wid & 1;
    const int l15  = lane & 15;
    const int l4   = lane >> 4;
    f32x4 acc[4][4];
#pragma unroll
    for (int i = 0; i < 4; ++i)
#pragma unroll
        for (int j = 0; j < 4; ++j) acc[i][j] = (f32x4){0.f, 0.f, 0.f, 0.f};
    const int a_tr = tid >> 3;
    const int a_tc = (tid & 7) * 8;
    const int kp2  = tid >> 4;
    const int n8   = (tid & 15) * 8;
    for (int kt = 0; kt < Kdim / 64; ++kt) {
        const int k0 = kt * 64;
        __syncthreads();
#pragma unroll
        for (int j = 0; j < 4; ++j) {
            const int ml = a_tr + 32 * j;
            const float* src = A + (size_t)(m0 + ml) * Kdim + (k0 + a_tc);
            const f32x4 x0 = *(const f32x4*)src;
            const f32x4 x1 = *(const f32x4*)(src + 4);
            union { bf16x8 v; unsigned short u[8]; } h;
            h.u[0] = f2bf(x0[0]); h.u[1] = f2bf(x0[1]);
            h.u[2] = f2bf(x0[2]); h.u[3] = f2bf(x0[3]);
            h.u[4] = f2bf(x1[0]); h.u[5] = f2bf(x1[1]);
            h.u[6] = f2bf(x1[2]); h.u[7] = f2bf(x1[3]);
            *(bf16x8*)(&As[ml * SA + (a_tc ^ ((ml & 7) << 3))]) = h.v;
        }
        {
            const int pr = kt * 32 + 2 * kp2;
            const int* wp = Wq + (size_t)pr * Ndim + (n0 + n8);
            const i32x4 r0a = *(const i32x4*)wp;
            const i32x4 r0b = *(const i32x4*)(wp + 4);
            const i32x4 r1a = *(const i32x4*)(wp + Ndim);
            const i32x4 r1b = *(const i32x4*)(wp + Ndim + 4);
            const int g = 2 * kt + (kp2 >> 3);
            const float* sp = Ws + (size_t)g * Ndim + (n0 + n8);
            const f32x4 s0 = *(const f32x4*)sp;
            const f32x4 s1 = *(const f32x4*)(sp + 4);
#pragma unroll
            for (int i = 0; i < 8; ++i) {
                const float s = (i < 4) ? s0[i] : s1[i - 4];
                const int b0 = (i < 4) ? r0a[i] : r0b[i - 4];
                const int b1 = (i < 4) ? r1a[i] : r1b[i - 4];
                union { unsigned long long v; unsigned short u[4]; } o;
                o.u[0] = f2bf((float)((b0 & 15) - 8) * s);
                o.u[1] = f2bf((float)(((b0 >> 4) & 15) - 8) * s);
                o.u[2] = f2bf((float)((b1 & 15) - 8) * s);
                o.u[3] = f2bf((float)(((b1 >> 4) & 15) - 8) * s);
                const int nl = n8 + i;
                const int swzz = ((nl ^ (nl >> 3)) & 7) << 3;
                *(unsigned long long*)(&Bs[nl * SA + ((4 * kp2) ^ swzz)]) = o.v;
            }
        }
        __syncthreads();
#pragma unroll
        for (int ks = 0; ks < 2; ++ks) {
            const int kb  = ks * 32 + l4 * 8;
            const int swa = (l15 & 7) << 3;
            bf16x8 af[4], bfr[4];
#pragma unroll
            for (int fm = 0; fm < 4; ++fm) {
                const int row = wr * 64 + fm * 16 + l15;
                af[fm] = *(const bf16x8*)(&As[row * SA + (kb ^ swa)]);
            }
#pragma unroll
            for (int fn = 0; fn < 4; ++fn) {
                const int nrow = wc * 64 + fn * 16 + l15;
                const int swb = ((nrow ^ (nrow >> 3)) & 7) << 3;
                bfr[fn] = *(const bf16x8*)(&Bs[nrow * SA + (kb ^ swb)]);
            }
#pragma unroll
            for (int fm = 0; fm < 4; ++fm)
#pragma unroll
                for (int fn = 0; fn < 4; ++fn)
                    acc[fm][fn] = __builtin_amdgcn_mfma_f32_16x16x32_bf16(
                        af[fm], bfr[fn], acc[fm][fn], 0, 0, 0);
        }
    }
    const int rb = l4 * 4;
    float bv[4];
#pragma unroll
    for (int fn = 0; fn < 4; ++fn)
        bv[fn] = Bias[n0 + wc * 64 + fn * 16 + l15];
#pragma unroll
    for (int fm = 0; fm < 4; ++fm) {
        const size_t mg = (size_t)(m0 + wr * 64 + fm * 16 + rb);
#pragma unroll
        for (int fn = 0; fn < 4; ++fn) {
            const int ng = n0 + wc * 64 + fn * 16 + l15;
            const float b = bv[fn];
#pragma unroll
            for (int r = 0; r < 4; ++r)
                Out[(mg + r) * Ndim + ng] = acc[fm][fn][r] + b;
        }
    }
}

extern "C" void kernel_launch(void* const* d_in, const int* in_sizes, int n_in,
                              void* d_out, int out_size, void* d_ws, size_t ws_size,
                              hipStream_t stream) {
    const float* A    = (const float*)d_in[0];
    const int* Wq     = (const int*)d_in[1];
    const float* Ws   = (const float*)d_in[2];
    const float* Bias = (const float*)d_in[3];
    float* Out        = (float*)d_out;

    const size_t needA = (size_t)Mdim * Kdim * 2;
    const size_t needW = (size_t)Ndim * Kdim * 2;
    if (ws_size >= needA + needW) {
        unsigned short* Ab = (unsigned short*)d_ws;
        unsigned short* Wt = (unsigned short*)((char*)d_ws + needA);
        cvtA_kernel<<<4096, 256, 0, stream>>>(A, Ab);
        deqW_kernel<<<(Kdim / 64) * (Ndim / 64), 256, 0, stream>>>(Wq, Ws, Wt);
        gemm256_kernel<<<(Mdim / 256) * (Ndim / 256), 512, 0, stream>>>(Ab, Wt, Bias, Out);
    } else {
        w4a32_fused_kernel<<<(Mdim / 128) * (Ndim / 128), 256, 0, stream>>>(A, Wq, Ws, Bias, Out);
    }
}

// Round 8
// 755.496 us; speedup vs baseline: 1.2408x; 1.0241x over previous
//
#include <hip/hip_runtime.h>
#include <hip/hip_bf16.h>
#include <stdint.h>

typedef __attribute__((ext_vector_type(8))) short bf16x8;
typedef __attribute__((ext_vector_type(4))) float f32x4;
typedef __attribute__((ext_vector_type(4))) int i32x4;

constexpr int Mdim = 8192;
constexpr int Ndim = 11008;
constexpr int Kdim = 4096;
constexpr int NT = Kdim / 64;            // 64 K-tiles of BK=64

__device__ __forceinline__ unsigned short f2bf(float f) {
    __bf16 h = (__bf16)f;
    return __builtin_bit_cast(unsigned short, h);
}

__device__ __forceinline__ void gload16(const unsigned short* g, unsigned short* lds) {
    __builtin_amdgcn_global_load_lds(
        (const __attribute__((address_space(1))) unsigned int*)g,
        (__attribute__((address_space(3))) unsigned int*)lds,
        16, 0, 0);
}

// ---------------- prepass 1: A fp32 -> bf16 ----------------
__global__ __launch_bounds__(256) void cvtA_kernel(const float* __restrict__ A,
                                                   unsigned short* __restrict__ Ab)
{
    const size_t total8 = (size_t)Mdim * Kdim / 8;
    for (size_t i = (size_t)blockIdx.x * blockDim.x + threadIdx.x; i < total8;
         i += (size_t)gridDim.x * blockDim.x) {
        const float* src = A + i * 8;
        const f32x4 x0 = *(const f32x4*)src;
        const f32x4 x1 = *(const f32x4*)(src + 4);
        union { bf16x8 v; unsigned short u[8]; } h;
        h.u[0] = f2bf(x0[0]); h.u[1] = f2bf(x0[1]);
        h.u[2] = f2bf(x0[2]); h.u[3] = f2bf(x0[3]);
        h.u[4] = f2bf(x1[0]); h.u[5] = f2bf(x1[1]);
        h.u[6] = f2bf(x1[2]); h.u[7] = f2bf(x1[3]);
        *(bf16x8*)(Ab + i * 8) = h.v;
    }
}

// ---------------- prepass 2: W int4 -> dequant bf16, transposed to [N][K] ----------------
__global__ __launch_bounds__(256) void deqW_kernel(const int* __restrict__ Wq,
                                                   const float* __restrict__ Ws,
                                                   unsigned short* __restrict__ Wt)
{
    __shared__ unsigned short T[64][72];
    const int kt = blockIdx.x % (Kdim / 64);
    const int nt = blockIdx.x / (Kdim / 64);
    const int k0 = kt * 64, n0 = nt * 64;
    const int t = threadIdx.x;

    const int pr   = t >> 3;
    const int nloc = (t & 7) * 8;
    const int* wp = Wq + (size_t)(k0 / 2 + pr) * Ndim + n0 + nloc;
    const i32x4 ra = *(const i32x4*)wp;
    const i32x4 rb = *(const i32x4*)(wp + 4);
    const int g = (k0 + 2 * pr) >> 5;
    const float* sp = Ws + (size_t)g * Ndim + n0 + nloc;
    const f32x4 s0 = *(const f32x4*)sp;
    const f32x4 s1 = *(const f32x4*)(sp + 4);
#pragma unroll
    for (int i = 0; i < 8; ++i) {
        const int v = (i < 4) ? ra[i] : rb[i - 4];
        const float s = (i < 4) ? s0[i] : s1[i - 4];
        union { unsigned int w; unsigned short u[2]; } o;
        o.u[0] = f2bf((float)((v & 15) - 8) * s);
        o.u[1] = f2bf((float)(((v >> 4) & 15) - 8) * s);
        *(unsigned int*)&T[nloc + i][2 * pr] = o.w;
    }
    __syncthreads();
    const int nl = t >> 2;
    const int ko = (t & 3) * 16;
    bf16x8 o0 = *(const bf16x8*)&T[nl][ko];
    bf16x8 o1 = *(const bf16x8*)&T[nl][ko + 8];
    unsigned short* dst = Wt + (size_t)(n0 + nl) * Kdim + k0 + ko;
    *(bf16x8*)dst = o0;
    *(bf16x8*)(dst + 8) = o1;
}

// ---- main GEMM: 256x256x64, 8 waves, cross-phase operand pipelining, 2 barriers/K-tile ----
__global__ __launch_bounds__(512, 2) void gemm256_kernel(
    const unsigned short* __restrict__ Ab,
    const unsigned short* __restrict__ Bt,
    const float* __restrict__ Bias,
    float* __restrict__ Out)
{
    // LDS: A region 4 slots (par,half) of 128x64 bf16, then B region 4 slots. 128 KiB.
    __shared__ unsigned short sh[65536];

    const int tid  = threadIdx.x;
    const int lane = tid & 63;
    const int wid  = tid >> 6;
    const int wr   = wid >> 2;               // 0..1 : M 128-row half
    const int wc   = wid & 3;                // 0..3 : N 64-col quarter
    const int l15  = lane & 15;
    const int l4   = lane >> 4;
    const int swz  = (l15 & 7) << 3;
    const int kb0  = l4 * 8;
    const int kb1  = 32 + l4 * 8;

    // XCD-aware bijective swizzle (1376 % 8 == 0), bm-major chunks per XCD
    const int nwg = (Mdim / 256) * (Ndim / 256);   // 1376
    const int cpx = nwg / 8;                        // 172
    const int wg  = ((int)blockIdx.x % 8) * cpx + (int)blockIdx.x / 8;
    const int nbn = Ndim / 256;                     // 43
    const int bm = wg / nbn, bn = wg % nbn;
    const int m0 = bm * 256, n0 = bn * 256;

    // staging per-thread addresses (pre-swizzled source, linear LDS dest)
    const int sr  = tid >> 3;                       // 0..63
    const int scl = ((tid & 7) * 8) ^ ((sr & 7) << 3);
    const int ldo = sr * 64 + (tid & 7) * 8;        // shorts; + j*4096
    const unsigned short* aSrc = Ab + (size_t)(m0 + sr) * Kdim + scl;
    const unsigned short* bSrc = Bt + (size_t)(n0 + sr) * Kdim + scl;

    auto stageA = [&](int tt, int h, int slot) {
        unsigned short* base = &sh[slot * 8192];
#pragma unroll
        for (int j = 0; j < 2; ++j)
            gload16(aSrc + (size_t)(h * 128 + 64 * j) * Kdim + tt * 64, base + ldo + j * 4096);
    };
    auto stageB = [&](int tt, int h, int slot) {
        unsigned short* base = &sh[32768 + slot * 8192];
#pragma unroll
        for (int j = 0; j < 2; ++j)
            gload16(bSrc + (size_t)(h * 128 + 64 * j) * Kdim + tt * 64, base + ldo + j * 4096);
    };

    f32x4 acc[8][4];
#pragma unroll
    for (int i = 0; i < 8; ++i)
#pragma unroll
        for (int j = 0; j < 4; ++j) acc[i][j] = (f32x4){0.f, 0.f, 0.f, 0.f};

    // prologue: tile0 (A0,A1,B0,B1) + tile1 B halves; wait tile0; barrier
    stageA(0, 0, 0); stageA(0, 1, 1);
    stageB(0, 0, 0); stageB(0, 1, 1);
    stageB(1, 0, 2); stageB(1, 1, 3);
    asm volatile("s_waitcnt vmcnt(4)" ::: "memory");
    __builtin_amdgcn_s_barrier();

    const int browb = (wc & 1) * 64;

    for (int t = 0; t < NT; ++t) {
        const int par = t & 1, parn = par ^ 1;
        const unsigned short* aslot = &sh[(par * 2 + wr) * 8192];
        const unsigned short* bslot = &sh[32768 + (par * 2 + (wc >> 1)) * 8192];

        bf16x8 a0[4][2], a1[4][2], b0[2][2], b1[2][2];

        // ---- phase 0: read A mh0 (8) + B nh0 (4); stage A(t+1) h0; MFMA mh0 x nh0 ----
#pragma unroll
        for (int f = 0; f < 4; ++f) {
            const int row = f * 16 + l15;
            a0[f][0] = *(const bf16x8*)&aslot[row * 64 + (kb0 ^ swz)];
            a0[f][1] = *(const bf16x8*)&aslot[row * 64 + (kb1 ^ swz)];
        }
#pragma unroll
        for (int f = 0; f < 2; ++f) {
            const int row = browb + f * 16 + l15;
            b0[f][0] = *(const bf16x8*)&bslot[row * 64 + (kb0 ^ swz)];
            b0[f][1] = *(const bf16x8*)&bslot[row * 64 + (kb1 ^ swz)];
        }
        if (t + 1 < NT) stageA(t + 1, 0, parn * 2 + 0);
        __builtin_amdgcn_s_setprio(1);
#pragma unroll
        for (int ks = 0; ks < 2; ++ks)
#pragma unroll
            for (int f = 0; f < 4; ++f)
#pragma unroll
                for (int fn = 0; fn < 2; ++fn)
                    acc[f][fn] = __builtin_amdgcn_mfma_f32_16x16x32_bf16(
                        a0[f][ks], b0[fn][ks], acc[f][fn], 0, 0, 0);
        __builtin_amdgcn_s_setprio(0);

        // ---- phase 1: read A mh1 (8, hides under p0 MFMA); stage A(t+1) h1; MFMA mh1 x nh0 ----
#pragma unroll
        for (int f = 0; f < 4; ++f) {
            const int row = 64 + f * 16 + l15;
            a1[f][0] = *(const bf16x8*)&aslot[row * 64 + (kb0 ^ swz)];
            a1[f][1] = *(const bf16x8*)&aslot[row * 64 + (kb1 ^ swz)];
        }
        if (t + 1 < NT) stageA(t + 1, 1, parn * 2 + 1);
        __builtin_amdgcn_s_setprio(1);
#pragma unroll
        for (int ks = 0; ks < 2; ++ks)
#pragma unroll
            for (int f = 0; f < 4; ++f)
#pragma unroll
                for (int fn = 0; fn < 2; ++fn)
                    acc[4 + f][fn] = __builtin_amdgcn_mfma_f32_16x16x32_bf16(
                        a1[f][ks], b0[fn][ks], acc[4 + f][fn], 0, 0, 0);
        __builtin_amdgcn_s_setprio(0);

        // ---- phase 2: read B nh1 (4, hides under p1 MFMA); MFMA mh0 x nh1 (a0 reused) ----
#pragma unroll
        for (int f = 0; f < 2; ++f) {
            const int row = browb + (2 + f) * 16 + l15;
            b1[f][0] = *(const bf16x8*)&bslot[row * 64 + (kb0 ^ swz)];
            b1[f][1] = *(const bf16x8*)&bslot[row * 64 + (kb1 ^ swz)];
        }
        __builtin_amdgcn_s_setprio(1);
#pragma unroll
        for (int ks = 0; ks < 2; ++ks)
#pragma unroll
            for (int f = 0; f < 4; ++f)
#pragma unroll
                for (int fn = 0; fn < 2; ++fn)
                    acc[f][2 + fn] = __builtin_amdgcn_mfma_f32_16x16x32_bf16(
                        a0[f][ks], b1[fn][ks], acc[f][2 + fn], 0, 0, 0);
        __builtin_amdgcn_s_setprio(0);

        // mid-barrier: every wave's B(t) reads completed (waits precede p0/p2 MFMA)
        asm volatile("" ::: "memory");
        __builtin_amdgcn_s_barrier();

        // ---- phase 3: stage B(t+2) both halves; MFMA mh1 x nh1 (a1,b1 reused) ----
        if (t + 2 < NT) { stageB(t + 2, 0, par * 2 + 0); stageB(t + 2, 1, par * 2 + 1); }
        __builtin_amdgcn_s_setprio(1);
#pragma unroll
        for (int ks = 0; ks < 2; ++ks)
#pragma unroll
            for (int f = 0; f < 4; ++f)
#pragma unroll
                for (int fn = 0; fn < 2; ++fn)
                    acc[4 + f][2 + fn] = __builtin_amdgcn_mfma_f32_16x16x32_bf16(
                        a1[f][ks], b1[fn][ks], acc[4 + f][2 + fn], 0, 0, 0);
        __builtin_amdgcn_s_setprio(0);

        // counted wait: oldest 8 of 12 outstanding = B(t+1)+A(t+1); leave B(t+2) in flight
        if (t < NT - 2)       asm volatile("s_waitcnt vmcnt(4)" ::: "memory");
        else if (t == NT - 2) asm volatile("s_waitcnt vmcnt(0)" ::: "memory");
        asm volatile("" ::: "memory");
        __builtin_amdgcn_s_barrier();   // end-barrier: staged data visible to all
    }

    // ---- epilogue: C/D col = lane&15, row = (lane>>4)*4 + r ----
    const int rb = l4 * 4;
    float bv[4];
#pragma unroll
    for (int fn = 0; fn < 4; ++fn)
        bv[fn] = Bias[n0 + wc * 64 + fn * 16 + l15];
#pragma unroll
    for (int fm = 0; fm < 8; ++fm) {
        const size_t mg = (size_t)(m0 + wr * 128 + fm * 16 + rb);
#pragma unroll
        for (int fn = 0; fn < 4; ++fn) {
            const int ng = n0 + wc * 64 + fn * 16 + l15;
            const float b = bv[fn];
#pragma unroll
            for (int r = 0; r < 4; ++r)
                Out[(mg + r) * Ndim + ng] = acc[fm][fn][r] + b;
        }
    }
}

// ---------------- fallback: fused kernel (if ws too small) ----------------
constexpr int SA = 72;
__global__ __launch_bounds__(256) void w4a32_fused_kernel(
    const float* __restrict__ A,
    const int* __restrict__ Wq,
    const float* __restrict__ Ws,
    const float* __restrict__ Bias,
    float* __restrict__ Out)
{
    __shared__ unsigned short As[128 * SA];
    __shared__ unsigned short Bs[128 * SA];
    const int tid = threadIdx.x;
    const int nbn = Ndim / 128;
    const int bn = blockIdx.x % nbn;
    const int bm = blockIdx.x / nbn;
    const int m0 = bm * 128, n0 = bn * 128;
    const int lane = tid & 63;
    const int wid  = tid >> 6;
    const int wr   = wid >> 1;
    const int wc   = wid & 1;
    const int l15  = lane & 15;
    const int l4   = lane >> 4;
    f32x4 acc[4][4];
#pragma unroll
    for (int i = 0; i < 4; ++i)
#pragma unroll
        for (int j = 0; j < 4; ++j) acc[i][j] = (f32x4){0.f, 0.f, 0.f, 0.f};
    const int a_tr = tid >> 3;
    const int a_tc = (tid & 7) * 8;
    const int kp2  = tid >> 4;
    const int n8   = (tid & 15) * 8;
    for (int kt = 0; kt < Kdim / 64; ++kt) {
        const int k0 = kt * 64;
        __syncthreads();
#pragma unroll
        for (int j = 0; j < 4; ++j) {
            const int ml = a_tr + 32 * j;
            const float* src = A + (size_t)(m0 + ml) * Kdim + (k0 + a_tc);
            const f32x4 x0 = *(const f32x4*)src;
            const f32x4 x1 = *(const f32x4*)(src + 4);
            union { bf16x8 v; unsigned short u[8]; } h;
            h.u[0] = f2bf(x0[0]); h.u[1] = f2bf(x0[1]);
            h.u[2] = f2bf(x0[2]); h.u[3] = f2bf(x0[3]);
            h.u[4] = f2bf(x1[0]); h.u[5] = f2bf(x1[1]);
            h.u[6] = f2bf(x1[2]); h.u[7] = f2bf(x1[3]);
            *(bf16x8*)(&As[ml * SA + (a_tc ^ ((ml & 7) << 3))]) = h.v;
        }
        {
            const int pr = kt * 32 + 2 * kp2;
            const int* wp = Wq + (size_t)pr * Ndim + (n0 + n8);
            const i32x4 r0a = *(const i32x4*)wp;
            const i32x4 r0b = *(const i32x4*)(wp + 4);
            const i32x4 r1a = *(const i32x4*)(wp + Ndim);
            const i32x4 r1b = *(const i32x4*)(wp + Ndim + 4);
            const int g = 2 * kt + (kp2 >> 3);
            const float* sp = Ws + (size_t)g * Ndim + (n0 + n8);
            const f32x4 s0 = *(const f32x4*)sp;
            const f32x4 s1 = *(const f32x4*)(sp + 4);
#pragma unroll
            for (int i = 0; i < 8; ++i) {
                const float s = (i < 4) ? s0[i] : s1[i - 4];
                const int b0 = (i < 4) ? r0a[i] : r0b[i - 4];
                const int b1 = (i < 4) ? r1a[i] : r1b[i - 4];
                union { unsigned long long v; unsigned short u[4]; } o;
                o.u[0] = f2bf((float)((b0 & 15) - 8) * s);
                o.u[1] = f2bf((float)(((b0 >> 4) & 15) - 8) * s);
                o.u[2] = f2bf((float)((b1 & 15) - 8) * s);
                o.u[3] = f2bf((float)(((b1 >> 4) & 15) - 8) * s);
                const int nl = n8 + i;
                const int swzz = ((nl ^ (nl >> 3)) & 7) << 3;
                *(unsigned long long*)(&Bs[nl * SA + ((4 * kp2) ^ swzz)]) = o.v;
            }
        }
        __syncthreads();
#pragma unroll
        for (int ks = 0; ks < 2; ++ks) {
            const int kb  = ks * 32 + l4 * 8;
            const int swa = (l15 & 7) << 3;
            bf16x8 af[4], bfr[4];
#pragma unroll
            for (int fm = 0; fm < 4; ++fm) {
                const int row = wr * 64 + fm * 16 + l15;
                af[fm] = *(const bf16x8*)(&As[row * SA + (kb ^ swa)]);
            }
#pragma unroll
            for (int fn = 0; fn < 4; ++fn) {
                const int nrow = wc * 64 + fn * 16 + l15;
                const int swb = ((nrow ^ (nrow >> 3)) & 7) << 3;
                bfr[fn] = *(const bf16x8*)(&Bs[nrow * SA + (kb ^ swb)]);
            }
#pragma unroll
            for (int fm = 0; fm < 4; ++fm)
#pragma unroll
                for (int fn = 0; fn < 4; ++fn)
                    acc[fm][fn] = __builtin_amdgcn_mfma_f32_16x16x32_bf16(
                        af[fm], bfr[fn], acc[fm][fn], 0, 0, 0);
        }
    }
    const int rb = l4 * 4;
    float bv[4];
#pragma unroll
    for (int fn = 0; fn < 4; ++fn)
        bv[fn] = Bias[n0 + wc * 64 + fn * 16 + l15];
#pragma unroll
    for (int fm = 0; fm < 4; ++fm) {
        const size_t mg = (size_t)(m0 + wr * 64 + fm * 16 + rb);
#pragma unroll
        for (int fn = 0; fn < 4; ++fn) {
            const int ng = n0 + wc * 64 + fn * 16 + l15;
            const float b = bv[fn];
#pragma unroll
            for (int r = 0; r < 4; ++r)
                Out[(mg + r) * Ndim + ng] = acc[fm][fn][r] + b;
        }
    }
}

extern "C" void kernel_launch(void* const* d_in, const int* in_sizes, int n_in,
                              void* d_out, int out_size, void* d_ws, size_t ws_size,
                              hipStream_t stream) {
    const float* A    = (const float*)d_in[0];
    const int* Wq     = (const int*)d_in[1];
    const float* Ws   = (const float*)d_in[2];
    const float* Bias = (const float*)d_in[3];
    float* Out        = (float*)d_out;

    const size_t needA = (size_t)Mdim * Kdim * 2;
    const size_t needW = (size_t)Ndim * Kdim * 2;
    if (ws_size >= needA + needW) {
        unsigned short* Ab = (unsigned short*)d_ws;
        unsigned short* Wt = (unsigned short*)((char*)d_ws + needA);
        cvtA_kernel<<<4096, 256, 0, stream>>>(A, Ab);
        deqW_kernel<<<(Kdim / 64) * (Ndim / 64), 256, 0, stream>>>(Wq, Ws, Wt);
        gemm256_kernel<<<(Mdim / 256) * (Ndim / 256), 512, 0, stream>>>(Ab, Wt, Bias, Out);
    } else {
        w4a32_fused_kernel<<<(Mdim / 128) * (Ndim / 128), 256, 0, stream>>>(A, Wq, Ws, Bias, Out);
    }
}